// Round 9
// baseline (50.186 us; speedup 1.0000x reference)
//
#include <hip/hip_runtime.h>
#include <math.h>

#define BB 2
#define NN 8192
#define NT 256
#define MAXJBI 32           // worst-case i-tiles (256-wide)
#define MAXJBJ 64           // worst-case j-tiles (128-wide)
#define JT 128              // j-tile width
#define NCOV (BB * NN / NT) // 64 cov-stat blocks (32 per sample)

// ws layout (floats):
#define SM_OFF 0            // 4 floats: smooth {num,den} per sample (atomic)
#define CNT_OFF 4           // 2 uints: compaction counters
#define DONE_OFF 6          // 1 uint: k45 gate
#define P1_OFF 16           // [64][8] k1 per-block partials
#define P2_OFF (P1_OFF + 64 * 8)        // [64][9] cov per-block partials (8 sums + max)
#define CDATA_OFF 1168                   // BB*NN float4 (aligned)
#define PM_OFF (CDATA_OFF + BB * NN * 4)
#define PARTIAL_OFF (PM_OFF + BB * NN)   // [MAXJBJ][BB*NN][3] floats (~12.6 MB)

// p1 values: 0=ref_sum 1=con_sum 2=n_pred 3=spx 4=spy 5=spz 6=n_gt 7=bm_sum
// p2 values: 0..5=cov(xx,xy,xz,yy,yz,zz) 6=sum_dm 7=sum_d2m 8=max_dm

__device__ __forceinline__ float wave_sum(float v) {
#pragma unroll
    for (int o = 32; o > 0; o >>= 1) v += __shfl_xor(v, o, 64);
    return v;
}

__device__ __forceinline__ float wave_max(float v) {
#pragma unroll
    for (int o = 32; o > 0; o >>= 1) v = fmaxf(v, __shfl_xor(v, o, 64));
    return v;
}

__device__ __forceinline__ float acc_ld(const float* p) {
    return __hip_atomic_load(p, __ATOMIC_RELAXED, __HIP_MEMORY_SCOPE_AGENT);
}

__global__ void kz(float* ws) {
    if (threadIdx.x < 8) ws[threadIdx.x] = 0.f;   // smacc + cnts + done
}

// per-point pass + boundary compaction; 64 blocks x 256 (R8-proven)
__global__ void __launch_bounds__(NT) k1(const float* __restrict__ logits, const float* __restrict__ olog,
                                         const float* __restrict__ h, const int* __restrict__ tgt,
                                         const float* __restrict__ pts, float* __restrict__ ws) {
    int gid = blockIdx.x * NT + threadIdx.x;
    int b = gid >> 13;
    int lane = threadIdx.x & 63;
    int wid = threadIdx.x >> 6;

    const float* L = logits + (size_t)gid * 3;
    float l0 = L[0], l1 = L[1], l2 = L[2];
    const float* O = olog + (size_t)gid * 3;
    float o0 = O[0], o1 = O[1], o2 = O[2];
    float hp = h[gid];
    int t = tgt[gid];
    const float* P = pts + (size_t)gid * 3;
    float px = P[0], py = P[1], pz = P[2];

    float m = fmaxf(l0, fmaxf(l1, l2));
    float e0 = __expf(l0 - m), e1 = __expf(l1 - m), e2 = __expf(l2 - m);
    float s = e0 + e1 + e2;
    float inv = 1.f / s;
    float p0 = e0 * inv, p1 = e1 * inv, p2 = e2 * inv;
    float ls = __logf(s);
    float lt = (t == 0) ? l0 : ((t == 1) ? l1 : l2);
    float nll = -(lt - m - ls);

    float mo = fmaxf(o0, fmaxf(o1, o2));
    float f0 = __expf(o0 - mo), f1 = __expf(o1 - mo), f2 = __expf(o2 - mo);
    float so = 1.f / (f0 + f1 + f2);
    float q0 = f0 * so, q1 = f1 * so, q2 = f2 * so;

    float con = (p0 - q0) * (p0 - q0) + (p1 - q1) * (p1 - q1) + (p2 - q2) * (p2 - q2);

    float bm = (hp > 0.3f && hp < 0.7f) ? 1.f : 0.f;
    float refc = nll * (1.f + bm);
    float pred = (l2 > l0 && l2 > l1) ? 1.f : 0.f;
    float gt = (t == 2) ? 1.f : 0.f;

    // ---- block-aggregated compaction: ONE atomic per block ----
    __shared__ unsigned int wcnt[4], woff[4];
    unsigned long long mask = __ballot(bm > 0.f);
    if (lane == 0) wcnt[wid] = (unsigned int)__popcll(mask);
    __syncthreads();
    if (threadIdx.x == 0) {
        unsigned int c0 = wcnt[0], c1 = wcnt[1], c2 = wcnt[2], c3 = wcnt[3];
        unsigned int tot = c0 + c1 + c2 + c3;
        unsigned int base = tot ? atomicAdd(((unsigned int*)(ws + CNT_OFF)) + b, tot) : 0u;
        woff[0] = base; woff[1] = base + c0; woff[2] = base + c0 + c1; woff[3] = base + c0 + c1 + c2;
    }
    __syncthreads();
    if (bm > 0.f) {
        unsigned int idx = woff[wid] + (unsigned int)__popcll(mask & ((1ull << lane) - 1ull));
        ((float4*)(ws + CDATA_OFF))[(size_t)b * NN + idx] = make_float4(px, py, pz, p2);
    }
    ws[PM_OFF + gid] = pred;

    // ---- block-reduce 8 values -> p1buf[blk][8] (no atomics) ----
    __shared__ float r1[4][8];
    float vals[8] = { refc, con, pred, pred * px, pred * py, pred * pz, gt, bm };
#pragma unroll
    for (int k = 0; k < 8; k++) {
        float v = wave_sum(vals[k]);
        if (lane == 0) r1[wid][k] = v;
    }
    __syncthreads();
    if (threadIdx.x < 8) {
        int k = threadIdx.x;
        ws[P1_OFF + blockIdx.x * 8 + k] = r1[0][k] + r1[1][k] + r1[2][k] + r1[3][k];
    }
}

// role-split: 64 cov blocks + pairwise tiles (256i x 128j)
__global__ void __launch_bounds__(NT) k23(const float* __restrict__ pts, float* __restrict__ ws) {
    unsigned int* cnts = (unsigned int*)(ws + CNT_OFF);
    int bid = blockIdx.x;

    if (bid < NCOV) {
        // ---- cov/dist stats; center from p1buf sums ----
        int gid = bid * NT + threadIdx.x;
        int b = bid >> 5;
        int lane = threadIdx.x & 63;
        int wid = threadIdx.x >> 6;

        __shared__ float cen[4][32];
        __shared__ float cenv[4];
        if (threadIdx.x < 128) {
            int k = threadIdx.x & 3, c = threadIdx.x >> 2;
            cen[k][c] = ws[P1_OFF + (b * 32 + c) * 8 + 2 + k];   // n, spx, spy, spz
        }
        __syncthreads();
        if (threadIdx.x < 4) {
            float s = 0.f;
            for (int c = 0; c < 32; c++) s += cen[threadIdx.x][c];
            cenv[threadIdx.x] = s;
        }
        __syncthreads();
        float n = cenv[0];
        float nz = fmaxf(n, 1.f);
        float cx = cenv[1] / nz, cy = cenv[2] / nz, cz = cenv[3] / nz;

        const float* P = pts + (size_t)gid * 3;
        float dx = P[0] - cx, dy = P[1] - cy, dz = P[2] - cz;
        float mM = ws[PM_OFF + gid];

        float mx = dx * mM, my = dy * mM, mz = dz * mM;
        float d = sqrtf(dx * dx + dy * dy + dz * dz + 1e-12f);
        float dm = d * mM;

        __shared__ float r2[4][9];
        float vals[8] = { mx * mx, mx * my, mx * mz, my * my, my * mz, mz * mz, dm, d * dm };
#pragma unroll
        for (int k = 0; k < 8; k++) {
            float v = wave_sum(vals[k]);
            if (lane == 0) r2[wid][k] = v;
        }
        {
            float v = wave_max(dm);
            if (lane == 0) r2[wid][8] = v;
        }
        __syncthreads();
        if (threadIdx.x < 8) {
            int k = threadIdx.x;
            ws[P2_OFF + bid * 9 + k] = r2[0][k] + r2[1][k] + r2[2][k] + r2[3][k];
        } else if (threadIdx.x == 8) {
            ws[P2_OFF + bid * 9 + 8] = fmaxf(fmaxf(r2[0][8], r2[1][8]), fmaxf(r2[2][8], r2[3][8]));
        }
        return;
    }

    // ---- pairwise ball-query tile: 256 i x 128 j (branchless, sentinel-padded) ----
    int tile = bid - NCOV;
    int b   = tile / (MAXJBI * MAXJBJ);
    int rel = tile % (MAXJBI * MAXJBJ);
    int ib = rel / MAXJBJ, jb = rel % MAXJBJ;
    int M = (int)cnts[b];
    if (ib * 256 >= M || jb * JT >= M) return;      // uniform block exit

    const float4* cd = (const float4*)(ws + CDATA_OFF) + (size_t)b * NN;
    int i = ib * 256 + (int)threadIdx.x;
    bool act = i < M;
    float4 me = cd[act ? i : 0];
    float xi = act ? me.x : 1e9f;

    __shared__ float4 sj[JT];
    if (threadIdx.x < JT) {
        int j = jb * JT + (int)threadIdx.x;
        sj[threadIdx.x] = (j < M) ? cd[j] : make_float4(1e9f, 1e9f, 1e9f, 0.f);
    }
    __syncthreads();

    float cnt = 0.f, s1 = 0.f, s2 = 0.f;
#pragma unroll 8
    for (int k = 0; k < JT; k++) {
        float4 v = sj[k];
        float dx = xi - v.x, dy = me.y - v.y, dz = me.z - v.z;
        float d2 = dx * dx + dy * dy + dz * dz;
        float wv = (d2 < 0.0025f) ? 1.f : 0.f;
        cnt += wv; s1 += wv * v.w; s2 += wv * (v.w * v.w);
    }
    float* p = ws + PARTIAL_OFF + ((size_t)jb * (BB * NN) + (size_t)b * NN + i) * 3;
    p[0] = cnt; p[1] = s1; p[2] = s2;
}

// smoothness var-reduce + gated finalize; 64 blocks x 256
__global__ void __launch_bounds__(NT) k45(float* __restrict__ ws, float* __restrict__ out) {
    int gid = blockIdx.x * NT + threadIdx.x;
    int b = blockIdx.x >> 5, i = gid & (NN - 1);
    int lane = threadIdx.x & 63;
    int wid = threadIdx.x >> 6;
    unsigned int* cnts = (unsigned int*)(ws + CNT_OFF);
    int M = (int)cnts[b];

    // ---- per-i smoothness variance (plain cached loads; partial from k23) ----
    float vsum = 0.f, vcnt = 0.f;
    if (i < M) {
        int JB = (M + JT - 1) / JT;
        float cnt = 0.f, s1 = 0.f, s2 = 0.f;
        for (int jb = 0; jb < JB; jb++) {
            const float* p = ws + PARTIAL_OFF + ((size_t)jb * (BB * NN) + (size_t)b * NN + i) * 3;
            cnt += p[0]; s1 += p[1]; s2 += p[2];
        }
        float var = (s2 - s1 * s1 / fmaxf(cnt, 1.f)) / fmaxf(cnt - 1.f, 1.f);
        float valid = (cnt > 1.f) ? 1.f : 0.f;
        vsum = var * valid; vcnt = valid;
    }
    __shared__ float red[4][2];
    vsum = wave_sum(vsum); vcnt = wave_sum(vcnt);
    if (lane == 0) { red[wid][0] = vsum; red[wid][1] = vcnt; }
    __syncthreads();
    if (threadIdx.x == 0) {
        float ns = red[0][0] + red[1][0] + red[2][0] + red[3][0];
        float nc = red[0][1] + red[1][1] + red[2][1] + red[3][1];
        if (ns != 0.f) atomicAdd(ws + SM_OFF + b * 2, ns);
        if (nc != 0.f) atomicAdd(ws + SM_OFF + b * 2 + 1, nc);
    }

    // ---- gate: last of 64 blocks finalizes ----
    __syncthreads();
    __threadfence();
    __shared__ int lastflag;
    if (threadIdx.x == 0)
        lastflag = (atomicAdd((unsigned int*)(ws + DONE_OFF), 1u) == 63u) ? 1 : 0;
    __syncthreads();
    if (!lastflag) return;

    // parallel-reduce p1buf[64][8], p2buf[64][9]
    __shared__ float t1[BB][8][32];
    __shared__ float t2[BB][9][32];
    __shared__ float ft1[BB][8];
    __shared__ float ft2[BB][9];
    int t = threadIdx.x;
    if (t < 64) {
        int c = t & 31, bb = t >> 5;
#pragma unroll
        for (int k = 0; k < 8; k++) t1[bb][k][c] = ws[P1_OFF + (bb * 32 + c) * 8 + k];
#pragma unroll
        for (int k = 0; k < 9; k++) t2[bb][k][c] = ws[P2_OFF + (bb * 32 + c) * 9 + k];
    }
    __syncthreads();
    if (t < 16) {
        int bb = t >> 3, k = t & 7;
        float s = 0.f;
        for (int c = 0; c < 32; c++) s += t1[bb][k][c];
        ft1[bb][k] = s;
    } else if (t < 34) {
        int idx = t - 16, bb = idx / 9, k = idx % 9;
        if (k < 8) {
            float s = 0.f;
            for (int c = 0; c < 32; c++) s += t2[bb][k][c];
            ft2[bb][k] = s;
        } else {
            float s = 0.f;
            for (int c = 0; c < 32; c++) s = fmaxf(s, t2[bb][8][c]);
            ft2[bb][8] = s;
        }
    }
    __syncthreads();
    if (t != 0) return;

    // ---- float32 finalize (tolerance is ~2% relative; f32 ample) ----
    float tot = 0.f;
    for (int bb = 0; bb < BB; bb++) {
        float refm = ft1[bb][0] / NN;
        float conm = ft1[bb][1] / (NN * 3);
        float n = ft1[bb][2];
        float nz = fmaxf(n, 1.f);

        float shape = 0.f;
        if (n >= 10.f) {
            float cxx = ft2[bb][0] / nz, cxy = ft2[bb][1] / nz, cxz = ft2[bb][2] / nz;
            float cyy = ft2[bb][3] / nz, cyz = ft2[bb][4] / nz, czz = ft2[bb][5] / nz;
            float q = (cxx + cyy + czz) * (1.f / 3.f);
            float pp1 = cxy * cxy + cxz * cxz + cyz * cyz;
            float pp2 = (cxx - q) * (cxx - q) + (cyy - q) * (cyy - q) + (czz - q) * (czz - q) + 2.f * pp1;
            float p = sqrtf(fmaxf(pp2, 0.f) * (1.f / 6.f));
            float ev0, ev1, ev2;
            if (p < 1e-20f) { ev0 = ev1 = ev2 = q; }
            else {
                float ip = 1.f / p;
                float b00 = (cxx - q) * ip, b11 = (cyy - q) * ip, b22 = (czz - q) * ip;
                float b01 = cxy * ip, b02 = cxz * ip, b12 = cyz * ip;
                float det = b00 * (b11 * b22 - b12 * b12)
                          - b01 * (b01 * b22 - b12 * b02)
                          + b02 * (b01 * b12 - b11 * b02);
                float r = fminf(1.f, fmaxf(-1.f, det * 0.5f));
                float phi = acosf(r) * (1.f / 3.f);
                float e1 = q + 2.f * p * __cosf(phi);
                float e3 = q + 2.f * p * __cosf(phi + 2.0943951f);
                float e2 = 3.f * q - e1 - e3;
                ev2 = e1; ev1 = e2; ev0 = e3;
            }
            float aa = ev2 + 1e-8f;
            float r1v = ev1 / aa - 1.f, r0v = ev0 / aa - 1.f;
            shape = r1v * r1v + r0v * r0v;
        }

        float sdm = ft2[bb][6], sd2m = ft2[bb][7], maxd = ft2[bb][8];
        float varc = (sd2m - sdm * sdm / nz) / fmaxf(n - 1.f, 1.f);
        float conn = (n >= 5.f) ? varc / (maxd + 1e-8f) : 0.f;

        float smn = acc_ld(ws + SM_OFF + bb * 2);
        float smd = acc_ld(ws + SM_OFF + bb * 2 + 1);
        float sm = (ft1[bb][7] >= 5.f) ? smn / fmaxf(smd, 1.f) : 0.f;

        float pv = ft1[bb][2], gv = ft1[bb][6];
        float vol = (pv - gv) * (pv - gv);
        float rel = fabsf(pv - gv) / fmaxf(gv, 1.f);
        float size = (gv > 0.f) ? vol + 0.5f * rel : vol;

        tot += 0.3f * refm + 0.2f * conm + 0.5f * shape + 0.3f * sm + 0.8f * size + 0.6f * conn;
    }
    out[0] = tot * (1.f / BB);
}

extern "C" void kernel_launch(void* const* d_in, const int* in_sizes, int n_in,
                              void* d_out, int out_size, void* d_ws, size_t ws_size,
                              hipStream_t stream) {
    const float* logits = (const float*)d_in[0];
    const float* olog   = (const float*)d_in[1];
    const float* h      = (const float*)d_in[2];
    const int*   tgt    = (const int*)d_in[3];
    const float* pts    = (const float*)d_in[4];
    float* out = (float*)d_out;
    float* ws  = (float*)d_ws;

    kz<<<1, 64, 0, stream>>>(ws);
    k1<<<BB * NN / NT, NT, 0, stream>>>(logits, olog, h, tgt, pts, ws);
    k23<<<NCOV + BB * MAXJBI * MAXJBJ, NT, 0, stream>>>(pts, ws);
    k45<<<NCOV, NT, 0, stream>>>(ws, out);
}

// Round 10
// 48.735 us; speedup vs baseline: 1.0298x; 1.0298x over previous
//
#include <hip/hip_runtime.h>
#include <math.h>

#define BB 2
#define NN 8192
#define MAXJB 32            // 256-wide tiles per sample (i and j)
#define NCOV 64             // cov-stat blocks (32 per sample, 256 thr)
#define K1B 128             // k1 blocks (128 thr each)
#define K45B 128            // k45 blocks (128 thr each)

// ws layout (float offsets):
#define SM_OFF 0            // 4 floats: smooth {num,den} per sample (atomic)
#define CNT_OFF 4           // 2 uints: compaction counters
#define DONE_OFF 6          // 1 uint: k45 gate
#define P1_OFF 16           // [K1B][8] k1 per-block partials
#define P2_OFF (P1_OFF + K1B * 8)        // [NCOV][9] cov per-block partials
#define CDATA_OFF 1616                    // BB*NN float4 (16B aligned)
#define PM_OFF (CDATA_OFF + BB * NN * 4)
#define PARTIAL_OFF (PM_OFF + BB * NN)    // [MAXJB][BB*NN] float4 (16B aligned)

// p1: 0=ref_sum 1=con_sum 2=n_pred 3=spx 4=spy 5=spz 6=n_gt 7=bm_sum
// p2: 0..5=cov(xx,xy,xz,yy,yz,zz) 6=sum_dm 7=sum_d2m 8=max_dm

__device__ __forceinline__ float wave_sum(float v) {
#pragma unroll
    for (int o = 32; o > 0; o >>= 1) v += __shfl_xor(v, o, 64);
    return v;
}

__device__ __forceinline__ float wave_max(float v) {
#pragma unroll
    for (int o = 32; o > 0; o >>= 1) v = fmaxf(v, __shfl_xor(v, o, 64));
    return v;
}

__device__ __forceinline__ float acc_ld(const float* p) {
    return __hip_atomic_load(p, __ATOMIC_RELAXED, __HIP_MEMORY_SCOPE_AGENT);
}

__global__ void kz(float* ws) {
    if (threadIdx.x < 8) ws[threadIdx.x] = 0.f;   // smacc + cnts + done
}

// per-point pass + boundary compaction; 128 blocks x 128 (2 waves/block)
__global__ void __launch_bounds__(128) k1(const float* __restrict__ logits, const float* __restrict__ olog,
                                          const float* __restrict__ h, const int* __restrict__ tgt,
                                          const float* __restrict__ pts, float* __restrict__ ws) {
    int gid = blockIdx.x * 128 + threadIdx.x;
    int b = gid >> 13;
    int lane = threadIdx.x & 63;
    int wid = threadIdx.x >> 6;     // 0..1

    const float* L = logits + (size_t)gid * 3;
    float l0 = L[0], l1 = L[1], l2 = L[2];
    const float* O = olog + (size_t)gid * 3;
    float o0 = O[0], o1 = O[1], o2 = O[2];
    float hp = h[gid];
    int t = tgt[gid];
    const float* P = pts + (size_t)gid * 3;
    float px = P[0], py = P[1], pz = P[2];

    float m = fmaxf(l0, fmaxf(l1, l2));
    float e0 = __expf(l0 - m), e1 = __expf(l1 - m), e2 = __expf(l2 - m);
    float s = e0 + e1 + e2;
    float inv = 1.f / s;
    float p0 = e0 * inv, p1 = e1 * inv, p2 = e2 * inv;
    float ls = __logf(s);
    float lt = (t == 0) ? l0 : ((t == 1) ? l1 : l2);
    float nll = -(lt - m - ls);

    float mo = fmaxf(o0, fmaxf(o1, o2));
    float f0 = __expf(o0 - mo), f1 = __expf(o1 - mo), f2 = __expf(o2 - mo);
    float so = 1.f / (f0 + f1 + f2);
    float q0 = f0 * so, q1 = f1 * so, q2 = f2 * so;

    float con = (p0 - q0) * (p0 - q0) + (p1 - q1) * (p1 - q1) + (p2 - q2) * (p2 - q2);

    float bm = (hp > 0.3f && hp < 0.7f) ? 1.f : 0.f;
    float refc = nll * (1.f + bm);
    float pred = (l2 > l0 && l2 > l1) ? 1.f : 0.f;
    float gt = (t == 2) ? 1.f : 0.f;

    // ---- block-aggregated compaction: ONE atomic per block ----
    __shared__ unsigned int wcnt[2], woff[2];
    unsigned long long mask = __ballot(bm > 0.f);
    if (lane == 0) wcnt[wid] = (unsigned int)__popcll(mask);
    __syncthreads();
    if (threadIdx.x == 0) {
        unsigned int c0 = wcnt[0], c1 = wcnt[1];
        unsigned int tot = c0 + c1;
        unsigned int base = tot ? atomicAdd(((unsigned int*)(ws + CNT_OFF)) + b, tot) : 0u;
        woff[0] = base; woff[1] = base + c0;
    }
    __syncthreads();
    if (bm > 0.f) {
        unsigned int idx = woff[wid] + (unsigned int)__popcll(mask & ((1ull << lane) - 1ull));
        ((float4*)(ws + CDATA_OFF))[(size_t)b * NN + idx] = make_float4(px, py, pz, p2);
    }
    ws[PM_OFF + gid] = pred;

    // ---- block-reduce 8 values -> p1buf[blk][8] (no atomics) ----
    __shared__ float r1[2][8];
    float vals[8] = { refc, con, pred, pred * px, pred * py, pred * pz, gt, bm };
#pragma unroll
    for (int k = 0; k < 8; k++) {
        float v = wave_sum(vals[k]);
        if (lane == 0) r1[wid][k] = v;
    }
    __syncthreads();
    if (threadIdx.x < 8) {
        int k = threadIdx.x;
        ws[P1_OFF + blockIdx.x * 8 + k] = r1[0][k] + r1[1][k];
    }
}

// role-split: 64 cov blocks + 2048 pairwise tiles (256i x 256j); 256 thr
__global__ void __launch_bounds__(256) k23(const float* __restrict__ pts, float* __restrict__ ws) {
    unsigned int* cnts = (unsigned int*)(ws + CNT_OFF);
    int bid = blockIdx.x;

    if (bid < NCOV) {
        // ---- cov/dist stats; center from p1buf sums (64 k1-chunks/sample) ----
        int gid = bid * 256 + threadIdx.x;
        int b = bid >> 5;
        int lane = threadIdx.x & 63;
        int wid = threadIdx.x >> 6;

        __shared__ float cen[4][64];
        __shared__ float cenv[4];
        {
            int k = threadIdx.x & 3, c = threadIdx.x >> 2;   // 256 threads = 4x64
            cen[k][c] = ws[P1_OFF + (b * 64 + c) * 8 + 2 + k];   // n, spx, spy, spz
        }
        __syncthreads();
        if (threadIdx.x < 4) {
            float s = 0.f;
            for (int c = 0; c < 64; c++) s += cen[threadIdx.x][c];
            cenv[threadIdx.x] = s;
        }
        __syncthreads();
        float n = cenv[0];
        float nz = fmaxf(n, 1.f);
        float cx = cenv[1] / nz, cy = cenv[2] / nz, cz = cenv[3] / nz;

        const float* P = pts + (size_t)gid * 3;
        float dx = P[0] - cx, dy = P[1] - cy, dz = P[2] - cz;
        float mM = ws[PM_OFF + gid];

        float mx = dx * mM, my = dy * mM, mz = dz * mM;
        float d = sqrtf(dx * dx + dy * dy + dz * dz + 1e-12f);
        float dm = d * mM;

        __shared__ float r2[4][9];
        float vals[8] = { mx * mx, mx * my, mx * mz, my * my, my * mz, mz * mz, dm, d * dm };
#pragma unroll
        for (int k = 0; k < 8; k++) {
            float v = wave_sum(vals[k]);
            if (lane == 0) r2[wid][k] = v;
        }
        {
            float v = wave_max(dm);
            if (lane == 0) r2[wid][8] = v;
        }
        __syncthreads();
        if (threadIdx.x < 8) {
            int k = threadIdx.x;
            ws[P2_OFF + bid * 9 + k] = r2[0][k] + r2[1][k] + r2[2][k] + r2[3][k];
        } else if (threadIdx.x == 8) {
            ws[P2_OFF + bid * 9 + 8] = fmaxf(fmaxf(r2[0][8], r2[1][8]), fmaxf(r2[2][8], r2[3][8]));
        }
        return;
    }

    // ---- pairwise ball-query tile (branchless, sentinel-padded) ----
    int tile = bid - NCOV;
    int b   = tile / (MAXJB * MAXJB);
    int rel = tile % (MAXJB * MAXJB);
    int ib = rel / MAXJB, jb = rel % MAXJB;
    int M = (int)cnts[b];
    if (ib * 256 >= M || jb * 256 >= M) return;     // uniform block exit

    const float4* cd = (const float4*)(ws + CDATA_OFF) + (size_t)b * NN;
    int i = ib * 256 + (int)threadIdx.x;
    bool act = i < M;
    float4 me = cd[act ? i : 0];
    float xi = act ? me.x : 1e9f;

    __shared__ float4 sj[256];
    int j = jb * 256 + (int)threadIdx.x;
    sj[threadIdx.x] = (j < M) ? cd[j] : make_float4(1e9f, 1e9f, 1e9f, 0.f);
    __syncthreads();

    float cnt = 0.f, s1 = 0.f, s2 = 0.f;
#pragma unroll 8
    for (int k = 0; k < 256; k++) {
        float4 v = sj[k];
        float dx = xi - v.x, dy = me.y - v.y, dz = me.z - v.z;
        float d2 = dx * dx + dy * dy + dz * dz;
        float wv = (d2 < 0.0025f) ? 1.f : 0.f;
        cnt += wv; s1 += wv * v.w; s2 += wv * (v.w * v.w);
    }
    // aligned float4, coalesced across i for fixed jb
    ((float4*)(ws + PARTIAL_OFF))[(size_t)jb * (BB * NN) + (size_t)b * NN + i] =
        make_float4(cnt, s1, s2, 0.f);
}

// smoothness var-reduce + gated finalize; 128 blocks x 128
__global__ void __launch_bounds__(128) k45(float* __restrict__ ws, float* __restrict__ out) {
    int gid = blockIdx.x * 128 + threadIdx.x;
    int b = gid >> 13, i = gid & (NN - 1);
    int lane = threadIdx.x & 63;
    int wid = threadIdx.x >> 6;
    unsigned int* cnts = (unsigned int*)(ws + CNT_OFF);
    int M = (int)cnts[b];

    // ---- per-i smoothness variance (plain cached float4 loads) ----
    float vsum = 0.f, vcnt = 0.f;
    if (i < M) {
        int JB = (M + 255) >> 8;
        float cnt = 0.f, s1 = 0.f, s2 = 0.f;
        const float4* pp = (const float4*)(ws + PARTIAL_OFF) + (size_t)b * NN + i;
#pragma unroll 4
        for (int jb = 0; jb < JB; jb++) {
            float4 p = pp[(size_t)jb * (BB * NN)];
            cnt += p.x; s1 += p.y; s2 += p.z;
        }
        float var = (s2 - s1 * s1 / fmaxf(cnt, 1.f)) / fmaxf(cnt - 1.f, 1.f);
        float valid = (cnt > 1.f) ? 1.f : 0.f;
        vsum = var * valid; vcnt = valid;
    }
    __shared__ float red[2][2];
    vsum = wave_sum(vsum); vcnt = wave_sum(vcnt);
    if (lane == 0) { red[wid][0] = vsum; red[wid][1] = vcnt; }
    __syncthreads();
    if (threadIdx.x == 0) {
        float ns = red[0][0] + red[1][0];
        float nc = red[0][1] + red[1][1];
        if (ns != 0.f) atomicAdd(ws + SM_OFF + b * 2, ns);
        if (nc != 0.f) atomicAdd(ws + SM_OFF + b * 2 + 1, nc);
    }

    // ---- gate: last of 128 blocks finalizes ----
    __syncthreads();
    __threadfence();
    __shared__ int lastflag;
    if (threadIdx.x == 0)
        lastflag = (atomicAdd((unsigned int*)(ws + DONE_OFF), 1u) == (unsigned int)(K45B - 1)) ? 1 : 0;
    __syncthreads();
    if (!lastflag) return;

    // parallel-reduce p1buf[128][8] (64 chunks/sample), p2buf[64][9] (32/sample)
    __shared__ float ft1[BB][8];
    __shared__ float ft2[BB][9];
    int t = threadIdx.x;
    if (t < 16) {
        int bb = t >> 3, k = t & 7;
        float s = 0.f;
        for (int c = 0; c < 64; c++) s += ws[P1_OFF + (bb * 64 + c) * 8 + k];
        ft1[bb][k] = s;
    } else if (t < 34) {
        int idx = t - 16, bb = idx / 9, k = idx % 9;
        if (k < 8) {
            float s = 0.f;
            for (int c = 0; c < 32; c++) s += ws[P2_OFF + (bb * 32 + c) * 9 + k];
            ft2[bb][k] = s;
        } else {
            float s = 0.f;
            for (int c = 0; c < 32; c++) s = fmaxf(s, ws[P2_OFF + (bb * 32 + c) * 9 + 8]);
            ft2[bb][8] = s;
        }
    }
    __syncthreads();
    if (t != 0) return;

    // ---- float32 finalize ----
    float tot = 0.f;
    for (int bb = 0; bb < BB; bb++) {
        float refm = ft1[bb][0] / NN;
        float conm = ft1[bb][1] / (NN * 3);
        float n = ft1[bb][2];
        float nz = fmaxf(n, 1.f);

        float shape = 0.f;
        if (n >= 10.f) {
            float cxx = ft2[bb][0] / nz, cxy = ft2[bb][1] / nz, cxz = ft2[bb][2] / nz;
            float cyy = ft2[bb][3] / nz, cyz = ft2[bb][4] / nz, czz = ft2[bb][5] / nz;
            float q = (cxx + cyy + czz) * (1.f / 3.f);
            float pp1 = cxy * cxy + cxz * cxz + cyz * cyz;
            float pp2 = (cxx - q) * (cxx - q) + (cyy - q) * (cyy - q) + (czz - q) * (czz - q) + 2.f * pp1;
            float p = sqrtf(fmaxf(pp2, 0.f) * (1.f / 6.f));
            float ev0, ev1, ev2;
            if (p < 1e-20f) { ev0 = ev1 = ev2 = q; }
            else {
                float ip = 1.f / p;
                float b00 = (cxx - q) * ip, b11 = (cyy - q) * ip, b22 = (czz - q) * ip;
                float b01 = cxy * ip, b02 = cxz * ip, b12 = cyz * ip;
                float det = b00 * (b11 * b22 - b12 * b12)
                          - b01 * (b01 * b22 - b12 * b02)
                          + b02 * (b01 * b12 - b11 * b02);
                float r = fminf(1.f, fmaxf(-1.f, det * 0.5f));
                float phi = acosf(r) * (1.f / 3.f);
                float e1 = q + 2.f * p * __cosf(phi);
                float e3 = q + 2.f * p * __cosf(phi + 2.0943951f);
                float e2 = 3.f * q - e1 - e3;
                ev2 = e1; ev1 = e2; ev0 = e3;
            }
            float aa = ev2 + 1e-8f;
            float r1v = ev1 / aa - 1.f, r0v = ev0 / aa - 1.f;
            shape = r1v * r1v + r0v * r0v;
        }

        float sdm = ft2[bb][6], sd2m = ft2[bb][7], maxd = ft2[bb][8];
        float varc = (sd2m - sdm * sdm / nz) / fmaxf(n - 1.f, 1.f);
        float conn = (n >= 5.f) ? varc / (maxd + 1e-8f) : 0.f;

        float smn = acc_ld(ws + SM_OFF + bb * 2);
        float smd = acc_ld(ws + SM_OFF + bb * 2 + 1);
        float sm = (ft1[bb][7] >= 5.f) ? smn / fmaxf(smd, 1.f) : 0.f;

        float pv = ft1[bb][2], gv = ft1[bb][6];
        float vol = (pv - gv) * (pv - gv);
        float rel = fabsf(pv - gv) / fmaxf(gv, 1.f);
        float size = (gv > 0.f) ? vol + 0.5f * rel : vol;

        tot += 0.3f * refm + 0.2f * conm + 0.5f * shape + 0.3f * sm + 0.8f * size + 0.6f * conn;
    }
    out[0] = tot * (1.f / BB);
}

extern "C" void kernel_launch(void* const* d_in, const int* in_sizes, int n_in,
                              void* d_out, int out_size, void* d_ws, size_t ws_size,
                              hipStream_t stream) {
    const float* logits = (const float*)d_in[0];
    const float* olog   = (const float*)d_in[1];
    const float* h      = (const float*)d_in[2];
    const int*   tgt    = (const int*)d_in[3];
    const float* pts    = (const float*)d_in[4];
    float* out = (float*)d_out;
    float* ws  = (float*)d_ws;

    kz<<<1, 64, 0, stream>>>(ws);
    k1<<<K1B, 128, 0, stream>>>(logits, olog, h, tgt, pts, ws);
    k23<<<NCOV + BB * MAXJB * MAXJB, 256, 0, stream>>>(pts, ws);
    k45<<<K45B, 128, 0, stream>>>(ws, out);
}